// Round 5
// baseline (1195.094 us; speedup 1.0000x reference)
//
#include <hip/hip_runtime.h>
#include <stdint.h>

// ParallelFcWithAttention: B=16384, F=10, D=512, H=8, DH=64
// v6 = v4 base with: (1) phase-1 K-loop processes 4 heads per pass (A-frags
// read once per k-chunk, shared by 4 heads; 32 intervals instead of 64;
// single 48KB B buffer staged per 32-k chunk, MFMA-overlapped drain),
// (2) shuffle-free softmax (no max-sub; denominator folded into PV),
// (3) phase 2 verbatim from v4 (BK=32 dbuf + counted vmcnt, ~100us).

typedef __bf16 bf16;
typedef __bf16 bf16x8 __attribute__((ext_vector_type(8)));
typedef float f32x4 __attribute__((ext_vector_type(4)));

#define EPS 1e-5f

static constexpr size_t O_ELEMS   = (size_t)16384 * 10 * 512;   // 83,886,080
static constexpr size_t O_BYTES   = O_ELEMS * 2;                // 167,772,160
static constexpr size_t WQKV_BYTES = (size_t)8 * 192 * 512 * 2; // 1,572,864

__device__ __forceinline__ void async_copy16(void* lds, const void* g) {
  // wave-uniform LDS base; HW scatters lane i at base + i*16; global addr per-lane
  __builtin_amdgcn_global_load_lds(
      (const __attribute__((address_space(1))) uint32_t*)g,
      (__attribute__((address_space(3))) uint32_t*)lds, 16, 0, 0);
}

// ---------------- pack weights to bf16 ----------------
// wqkv layout: [h][0:64 = Wq rows h*64.., 64:128 = Wk, 128:192 = Wv][512]
__global__ __launch_bounds__(256) void pack_weights(
    const float* __restrict__ Wq, const float* __restrict__ Wk,
    const float* __restrict__ Wv, const float* __restrict__ Wo,
    bf16* __restrict__ wqkv, bf16* __restrict__ wob) {
  int idx = blockIdx.x * 256 + threadIdx.x;
#pragma unroll
  for (int u = 0; u < 4; ++u) {
    int i = idx + u * 262144;
    if (i < 786432) {
      int pr = i >> 9, k = i & 511;
      int h = pr / 192, w = pr - h * 192;
      int t = w >> 6, r = w & 63;
      const float* src = (t == 0) ? Wq : ((t == 1) ? Wk : Wv);
      wqkv[i] = (bf16)src[(h * 64 + r) * 512 + k];
    } else {
      int j = i - 786432;
      wob[j] = (bf16)Wo[j];
    }
  }
}

// ---------------- fused kernel ----------------
// 512 threads, 8 batch elems (80 rows) per block. 1 block/CU. LDS 131072 B.
// phase 1: sA @0 [8 slabs][80 rows][128B] XOR-swizzled            81920
//          sB @81920 [4 heads][96 lines][128B] paired-row layout  49152
//          epilogue overlay in sB region: sQK @81920 (22528),
//            vbuf @104448 (10240), scp @114688 (3840)
// phase 2 overlay: Ab0@0 Ab1@5120 | Bb0@10240 Bb1@43008 (end 75776)
//          lnb @0 [80][520] bf16 (83200) | partial @83200 | stats @85760
__global__ __launch_bounds__(512, 2) void kern_fused(
    const float* __restrict__ x, const float* __restrict__ Wf,
    const float* __restrict__ bfv, const bf16* __restrict__ wqkv,
    const float* __restrict__ bq, const float* __restrict__ bk,
    const float* __restrict__ bv, bf16* __restrict__ O,
    const bf16* __restrict__ wob, const float* __restrict__ bo,
    const float* __restrict__ gamma, const float* __restrict__ beta,
    float* __restrict__ out) {
  __shared__ __align__(16) char smem[131072];
  char* sA  = smem;
  char* sB  = smem + 81920;
  char* sQK = smem + 81920;                // epilogue overlay (sB dead then)
  bf16* vbuf = (bf16*)(smem + 104448);
  float* scp = (float*)(smem + 114688);

  const int tid = threadIdx.x;
  const int wave = tid >> 6;
  const int lane = tid & 63;
  const int lm = lane & 15;
  const int lg = lane >> 4;
  const int wm = wave >> 2;
  const int wn = wave & 3;
  const int b0 = blockIdx.x * 8;
  const int x7 = lm & 7;
  // staging lane geometry (paired-row layout; same math as phase 2):
  const int srow  = lane >> 2;                       // row within 16-row copy
  const int sgran = (lane & 3) ^ ((lane >> 3) & 3);  // pre-swizzled granule

  // stage k-chunk j_ (32 k-elems = 64B/row) of heads g_*4..g_*4+3 into sB.
  // 48 copies of 1024B (8 lines); 6 per wave. LDS base wave-uniform.
#define STAGE1(g_, j_)                                                          \
  {                                                                             \
    _Pragma("unroll")                                                           \
    for (int jb = 0; jb < 6; ++jb) {                                            \
      int c = wave + 8 * jb;                                                    \
      int hh = c / 12;                                                          \
      int L0 = (c - hh * 12) * 8;                                               \
      async_copy16(sB + hh * 12288 + L0 * 128,                                  \
          (const char*)wqkv + (size_t)(g_) * 786432 + (size_t)hh * 196608 +     \
          (size_t)(L0 * 2 + srow) * 1024 + (size_t)(j_) * 64 + sgran * 16);     \
    }                                                                           \
  }

  // ---- prologue: stage (g=0, j=0) (hides under P compute) ----
  STAGE1(0, 0);

  // ---- compute P = relu(x*Wf + bf) into sA (80 real rows) ----
#pragma unroll
  for (int it = 0; it < 10; ++it) {
    int c = tid + it * 512;                // 5120 chunks: c = s*640 + r*8 + kcp
    int s = c / 640, rem = c - s * 640;
    int r = rem >> 3, kcp = rem & 7;
    int kc = kcp ^ (r & 7);
    int k = s * 64 + kc * 8;
    int bl = r / 10, f = r - bl * 10;
    float xv = x[(b0 + bl) * 10 + f];
    const float* wf = Wf + f * 512 + k;
    const float* bp = bfv + f * 512 + k;
    bf16x8 pv;
#pragma unroll
    for (int j = 0; j < 8; ++j) pv[j] = (bf16)fmaxf(xv * wf[j] + bp[j], 0.f);
    *(bf16x8*)(sA + s * 10240 + r * 128 + kcp * 16) = pv;
  }
  __syncthreads();   // P visible + stage(0,0) landed

  // B-frag LDS offsets are k-chunk invariant: precompute per nt
  int noff[3];
#pragma unroll
  for (int nt = 0; nt < 3; ++nt) {
    int n = wn * 48 + nt * 16 + lm, line = n >> 1;
    noff[nt] = line * 128 + (n & 1) * 64 + ((lg ^ (line & 3)) << 4);
  }

  for (int g = 0; g < 2; ++g) {
    f32x4 acc[4][3][3];
#pragma unroll
    for (int e = 0; e < 4; ++e)
#pragma unroll
      for (int i = 0; i < 3; ++i)
#pragma unroll
        for (int j = 0; j < 3; ++j) { f32x4 z = {0.f, 0.f, 0.f, 0.f}; acc[e][i][j] = z; }

    for (int j = 0; j < 16; ++j) {       // 16 k-chunks of 32
      const int ch = (((j & 1) * 4 + lg) ^ x7) << 4;
      const char* sAj = sA + (j >> 1) * 10240;
      bf16x8 af[3];
#pragma unroll
      for (int mt = 0; mt < 3; ++mt)
        if (mt < 2 || wm == 0)
          af[mt] = *(const bf16x8*)(sAj + (wm * 48 + mt * 16 + lm) * 128 + ch);
      bf16x8 bA[2][3], bB[2][3];
#pragma unroll
      for (int e = 0; e < 2; ++e)
#pragma unroll
        for (int nt = 0; nt < 3; ++nt)
          bA[e][nt] = *(const bf16x8*)(sB + e * 12288 + noff[nt]);
#pragma unroll
      for (int e = 0; e < 2; ++e)
#pragma unroll
        for (int nt = 0; nt < 3; ++nt)
          bB[e][nt] = *(const bf16x8*)(sB + (e + 2) * 12288 + noff[nt]);
      // heads 0,1 of the group (compiler inserts partial lgkmcnt waits)
      __builtin_amdgcn_s_setprio(1);
#pragma unroll
      for (int e = 0; e < 2; ++e)
#pragma unroll
        for (int mt = 0; mt < 3; ++mt)
          if (mt < 2 || wm == 0)
#pragma unroll
            for (int nt = 0; nt < 3; ++nt)
              acc[e][mt][nt] = __builtin_amdgcn_mfma_f32_16x16x32_bf16(af[mt], bA[e][nt], acc[e][mt][nt], 0, 0, 0);
      __builtin_amdgcn_s_setprio(0);
      asm volatile("s_waitcnt lgkmcnt(0)" ::: "memory");   // ALL sB reads done
      __builtin_amdgcn_sched_barrier(0);
      __builtin_amdgcn_s_barrier();                        // sB free for re-stage
      __builtin_amdgcn_sched_barrier(0);
      if (j < 15) {
        STAGE1(g, j + 1);                                  // DMA in flight...
        __builtin_amdgcn_sched_barrier(0);
      }
      // heads 2,3: register-only MFMAs overlap the staging flight
      __builtin_amdgcn_s_setprio(1);
#pragma unroll
      for (int e = 0; e < 2; ++e)
#pragma unroll
        for (int mt = 0; mt < 3; ++mt)
          if (mt < 2 || wm == 0)
#pragma unroll
            for (int nt = 0; nt < 3; ++nt)
              acc[e + 2][mt][nt] = __builtin_amdgcn_mfma_f32_16x16x32_bf16(af[mt], bB[e][nt], acc[e + 2][mt][nt], 0, 0, 0);
      __builtin_amdgcn_s_setprio(0);
      if (j < 15) {
        asm volatile("s_waitcnt vmcnt(0)" ::: "memory");   // chunk j+1 landed
        __builtin_amdgcn_sched_barrier(0);
        __builtin_amdgcn_s_barrier();
        __builtin_amdgcn_sched_barrier(0);
      }
    }

    // ---- per-head epilogues (4 heads); sB region is scratch now ----
#pragma unroll
    for (int e = 0; e < 4; ++e) {
      const int h = g * 4 + e;
      // spill q,k (+bias) -> sQK (swizzled), v (+bias) -> vbuf
      {
        float bias[3];
#pragma unroll
        for (int nt = 0; nt < 3; ++nt) {
          int col = wn * 48 + nt * 16 + lm;
          bias[nt] = (col < 64) ? bq[h * 64 + col]
                   : (col < 128) ? bk[h * 64 + col - 64]
                   : bv[h * 64 + col - 128];
        }
#pragma unroll
        for (int mt = 0; mt < 3; ++mt) {
          int rowb = wm * 48 + mt * 16 + lg * 4;
          if (rowb < 80) {
#pragma unroll
            for (int r = 0; r < 4; ++r) {
              int rw = rowb + r;
#pragma unroll
              for (int nt = 0; nt < 3; ++nt) {
                int col = wn * 48 + nt * 16 + lm;
                float val = acc[e][mt][nt][r] + bias[nt];
                if (col < 128)
                  *(bf16*)(sQK + rw * 256 + (((col >> 3) ^ (rw & 7)) << 4) + (col & 7) * 2) = (bf16)val;
                else
                  vbuf[rw * 64 + (col - 128)] = (bf16)val;
              }
            }
          }
        }
      }
      __syncthreads();   // qkv visible to all waves

      // scores via MFMA (wave = local batch); store UNNORMALIZED exp (no max-sub:
      // |score| <~ 10 analytically, e^10 = 2.2e4 is f32-safe; softmax identity holds)
      {
        const int bb = wave;
        f32x4 sv = {0.f, 0.f, 0.f, 0.f};
        const int rowa = bb * 10 + lm;     // lm>=10: garbage rows, masked below
        const int x7r = rowa & 7;
#pragma unroll
        for (int kk = 0; kk < 2; ++kk) {
          bf16x8 qf = *(const bf16x8*)(sQK + rowa * 256 + (((kk * 4 + lg) ^ x7r) << 4));
          bf16x8 kf = *(const bf16x8*)(sQK + rowa * 256 + (((8 + kk * 4 + lg) ^ x7r) << 4));
          sv = __builtin_amdgcn_mfma_f32_16x16x32_bf16(qf, kf, sv, 0, 0, 0);
        }
#pragma unroll
        for (int r = 0; r < 4; ++r) {
          int i = lg * 4 + r;
          if (i < 10 && lm < 12) {
            float ev = (lm < 10) ? __expf(sv[r] * 0.125f) : 0.f;
            scp[(bb * 10 + i) * 12 + lm] = ev;
          }
        }
      }
      // PV (lane <-> d); denominator folded in (scp[bb] written by this wave,
      // vbuf covered by the spill barrier) -> no extra barrier
      {
        const int bb = wave;
        const int d = lane;
        float vv[10];
#pragma unroll
        for (int jv = 0; jv < 10; ++jv) vv[jv] = (float)vbuf[(bb * 10 + jv) * 64 + d];
        bf16* Obp = O + ((size_t)(b0 + bb) * 10) * 512 + h * 64 + d;
#pragma unroll
        for (int i = 0; i < 10; ++i) {
          const float* ar = scp + (bb * 10 + i) * 12;
          f32x4 a0 = *(const f32x4*)ar;
          f32x4 a1 = *(const f32x4*)(ar + 4);
          float s8 = ar[8], s9 = ar[9];
          float ssum = a0[0] + a0[1] + a0[2] + a0[3] + a1[0] + a1[1] + a1[2] + a1[3] + s8 + s9;
          float o = a0[0] * vv[0] + a0[1] * vv[1] + a0[2] * vv[2] + a0[3] * vv[3]
                  + a1[0] * vv[4] + a1[1] * vv[5] + a1[2] * vv[6] + a1[3] * vv[7]
                  + s8 * vv[8] + s9 * vv[9];
          Obp[(size_t)i * 512] = (bf16)(o / ssum);
        }
      }
      __syncthreads();   // protect sQK/vbuf/scp before next head / next stage
    }

    if (g == 0) {        // stage first chunk of heads 4..7 (region free now)
      STAGE1(1, 0);
      asm volatile("s_waitcnt vmcnt(0)" ::: "memory");
      __builtin_amdgcn_sched_barrier(0);
      __builtin_amdgcn_s_barrier();
      __builtin_amdgcn_sched_barrier(0);
    }
  }

  // ================= Phase 2: O @ Wo^T + bo -> LN -> sum over F =================
  // v4 verbatim: BK=32, dbuf A+B, raw barriers + counted vmcnt, paired-row layout.
  {
    char* Ab0 = smem;
    char* Ab1 = smem + 5120;
    char* Bb0 = smem + 10240;
    char* Bb1 = smem + 43008;
    float* partial = (float*)(smem + 83200);  // [80][4][2]
    float* stats   = (float*)(smem + 85760);  // [80][2]
    const char* Ob = (const char*)(O + (size_t)blockIdx.x * 80 * 512);
    const char* Wb = (const char*)wob;

    f32x4 acc[3][8];
#pragma unroll
    for (int i = 0; i < 3; ++i)
#pragma unroll
      for (int j = 0; j < 8; ++j) { f32x4 z = {0.f, 0.f, 0.f, 0.f}; acc[i][j] = z; }

#define STAGE2(AbN, BbN, s_)                                                     \
    {                                                                            \
      size_t co = (size_t)(s_) * 64 + sgran * 16;                                \
      _Pragma("unroll")                                                          \
      for (int j = 0; j < 4; ++j) {                                              \
        int R0 = (wave * 4 + j) * 16;                                            \
        async_copy16((BbN) + R0 * 64, Wb + (size_t)(R0 + srow) * 1024 + co);     \
      }                                                                          \
      if (wave < 5) {                                                            \
        int R0 = wave * 16;                                                      \
        async_copy16((AbN) + R0 * 64, Ob + (size_t)(R0 + srow) * 1024 + co);     \
      }                                                                          \
    }

    STAGE2(Ab0, Bb0, 0);                   // prologue

    for (int s = 0; s < 16; ++s) {
      char* AbC = (s & 1) ? Ab1 : Ab0;
      char* BbC = (s & 1) ? Bb1 : Bb0;
      char* AbN = (s & 1) ? Ab0 : Ab1;
      char* BbN = (s & 1) ? Bb0 : Bb1;
      if (s != 15) {
        STAGE2(AbN, BbN, s + 1);
        if (wave < 5) asm volatile("s_waitcnt vmcnt(5)" ::: "memory");
        else          asm volatile("s_waitcnt vmcnt(4)" ::: "memory");
      } else {
        asm volatile("s_waitcnt vmcnt(0)" ::: "memory");
      }
      __builtin_amdgcn_sched_barrier(0);
      __builtin_amdgcn_s_barrier();        // slab s visible
      __builtin_amdgcn_sched_barrier(0);

      bf16x8 a2[3], b2[8];
#pragma unroll
      for (int mt = 0; mt < 3; ++mt)
        if (mt < 2 || wm == 0) {
          int m = wm * 48 + mt * 16 + lm;
          a2[mt] = *(const bf16x8*)(AbC + (m >> 1) * 128 + (m & 1) * 64 + (((lg ^ ((m >> 1) & 3))) << 4));
        }
#pragma unroll
      for (int nt = 0; nt < 8; ++nt) {
        int n = wn * 128 + nt * 16 + lm;
        b2[nt] = *(const bf16x8*)(BbC + (n >> 1) * 128 + (n & 1) * 64 + (((lg ^ ((n >> 1) & 3))) << 4));
      }
      __builtin_amdgcn_s_setprio(1);
#pragma unroll
      for (int mt = 0; mt < 3; ++mt)
        if (mt < 2 || wm == 0)
#pragma unroll
          for (int nt = 0; nt < 8; ++nt)
            acc[mt][nt] = __builtin_amdgcn_mfma_f32_16x16x32_bf16(a2[mt], b2[nt], acc[mt][nt], 0, 0, 0);
      __builtin_amdgcn_s_setprio(0);

      asm volatile("s_waitcnt lgkmcnt(0)" ::: "memory");
      __builtin_amdgcn_sched_barrier(0);
      __builtin_amdgcn_s_barrier();        // release slab s buffers
      __builtin_amdgcn_sched_barrier(0);
    }

    // + bias
#pragma unroll
    for (int nt = 0; nt < 8; ++nt) {
      float bb = bo[wn * 128 + nt * 16 + lm];
#pragma unroll
      for (int mt = 0; mt < 3; ++mt)
#pragma unroll
        for (int r = 0; r < 4; ++r) acc[mt][nt][r] += bb;
    }

    // per-row mean/var: lane-local over 8 nt, then xor-shuffle across 16-lane col group
#pragma unroll
    for (int mt = 0; mt < 3; ++mt)
#pragma unroll
      for (int r = 0; r < 4; ++r) {
        float s1 = 0.f, s2 = 0.f;
#pragma unroll
        for (int nt = 0; nt < 8; ++nt) { float v = acc[mt][nt][r]; s1 += v; s2 += v * v; }
#pragma unroll
        for (int off = 1; off < 16; off <<= 1) {
          s1 += __shfl_xor(s1, off);
          s2 += __shfl_xor(s2, off);
        }
        if (lm == 0) {
          int row = wm * 48 + mt * 16 + lg * 4 + r;
          if (row < 80) {
            partial[(row * 4 + wn) * 2]     = s1;
            partial[(row * 4 + wn) * 2 + 1] = s2;
          }
        }
      }
    __syncthreads();
    if (tid < 80) {
      float s1 = 0.f, s2 = 0.f;
#pragma unroll
      for (int w = 0; w < 4; ++w) {
        s1 += partial[(tid * 4 + w) * 2];
        s2 += partial[(tid * 4 + w) * 2 + 1];
      }
      float mu = s1 * (1.f / 512.f);
      float var = s2 * (1.f / 512.f) - mu * mu;
      stats[tid * 2]     = mu;
      stats[tid * 2 + 1] = rsqrtf(var + EPS);
    }
    __syncthreads();
    // normalized values -> LDS bf16 (GEMM buffers dead), stride 520
    bf16* lnb = (bf16*)smem;
#pragma unroll
    for (int mt = 0; mt < 3; ++mt)
#pragma unroll
      for (int r = 0; r < 4; ++r) {
        int row = wm * 48 + mt * 16 + lg * 4 + r;
        if (row < 80) {
          float mu = stats[row * 2], rr = stats[row * 2 + 1];
#pragma unroll
          for (int nt = 0; nt < 8; ++nt) {
            int col = wn * 128 + nt * 16 + lm;
            lnb[row * 520 + col] = (bf16)((acc[mt][nt][r] - mu) * rr);
          }
        }
      }
    __syncthreads();
    // out[b,n] = gamma[n]*sum_f lnv + 10*beta[n]
#pragma unroll
    for (int u = 0; u < 8; ++u) {
      int id = tid + u * 512;              // 4096 outputs: 8b x 512n
      int b = id >> 9, n = id & 511;
      float ssum = 0.f;
#pragma unroll
      for (int f = 0; f < 10; ++f) ssum += (float)lnb[(b * 10 + f) * 520 + n];
      out[((size_t)blockIdx.x * 8 + b) * 512 + n] = gamma[n] * ssum + 10.f * beta[n];
    }
  }
#undef STAGE1
#undef STAGE2
}

extern "C" void kernel_launch(void* const* d_in, const int* in_sizes, int n_in,
                              void* d_out, int out_size, void* d_ws, size_t ws_size,
                              hipStream_t stream) {
  const float* x     = (const float*)d_in[0];
  const float* Wf    = (const float*)d_in[1];
  const float* bfv   = (const float*)d_in[2];
  const float* Wq    = (const float*)d_in[3];
  const float* Wk    = (const float*)d_in[4];
  const float* Wv    = (const float*)d_in[5];
  const float* bq    = (const float*)d_in[6];
  const float* bk    = (const float*)d_in[7];
  const float* bv    = (const float*)d_in[8];
  const float* Wo    = (const float*)d_in[9];
  const float* bo    = (const float*)d_in[10];
  const float* gamma = (const float*)d_in[11];
  const float* beta  = (const float*)d_in[12];
  float* out = (float*)d_out;

  char* ws = (char*)d_ws;
  bf16* O    = (bf16*)ws;                              // 167,772,160 B
  bf16* wqkv = (bf16*)(ws + O_BYTES);                  // 1,572,864 B
  bf16* wob  = (bf16*)(ws + O_BYTES + WQKV_BYTES);     // 524,288 B

  pack_weights<<<1024, 256, 0, stream>>>(Wq, Wk, Wv, Wo, wqkv, wob);
  kern_fused<<<2048, 512, 0, stream>>>(x, Wf, bfv, wqkv, bq, bk, bv, O,
                                       wob, bo, gamma, beta, out);
}

// Round 6
// 962.519 us; speedup vs baseline: 1.2416x; 1.2416x over previous
//
#include <hip/hip_runtime.h>
#include <stdint.h>

// ParallelFcWithAttention: B=16384, F=10, D=512, H=8, DH=64
// v7 = v4 skeleton + register-safe 2-head grouping:
//  - K-loop processes 2 heads per pass (acc[2][3][3]=72 AGPR, no spill);
//    A-frags read once, shared by both heads; B dbuf 2x24KB, v4's counted
//    vmcnt(3) staging; paired-row XOR LDS layout (v6-verified formulas).
//  - shuffle-free softmax (v6-verified): unnormalized exp, denom folded in PV.
//  - paired epilogue: both heads spill->1 barrier; V interleaved (1 b32 = both
//    heads); scp rows read as 3x b128.
//  - phase 2 verbatim from v4 (BK=32 dbuf + counted vmcnt, ~100us).

typedef __bf16 bf16;
typedef __bf16 bf16x8 __attribute__((ext_vector_type(8)));
typedef float f32x4 __attribute__((ext_vector_type(4)));

#define EPS 1e-5f

static constexpr size_t O_ELEMS   = (size_t)16384 * 10 * 512;   // 83,886,080
static constexpr size_t O_BYTES   = O_ELEMS * 2;                // 167,772,160
static constexpr size_t WQKV_BYTES = (size_t)8 * 192 * 512 * 2; // 1,572,864

__device__ __forceinline__ void async_copy16(void* lds, const void* g) {
  // wave-uniform LDS base; HW scatters lane i at base + i*16; global addr per-lane
  __builtin_amdgcn_global_load_lds(
      (const __attribute__((address_space(1))) uint32_t*)g,
      (__attribute__((address_space(3))) uint32_t*)lds, 16, 0, 0);
}

// ---------------- pack weights to bf16 ----------------
// wqkv layout: [h][0:64 = Wq rows h*64.., 64:128 = Wk, 128:192 = Wv][512]
__global__ __launch_bounds__(256) void pack_weights(
    const float* __restrict__ Wq, const float* __restrict__ Wk,
    const float* __restrict__ Wv, const float* __restrict__ Wo,
    bf16* __restrict__ wqkv, bf16* __restrict__ wob) {
  int idx = blockIdx.x * 256 + threadIdx.x;
#pragma unroll
  for (int u = 0; u < 4; ++u) {
    int i = idx + u * 262144;
    if (i < 786432) {
      int pr = i >> 9, k = i & 511;
      int h = pr / 192, w = pr - h * 192;
      int t = w >> 6, r = w & 63;
      const float* src = (t == 0) ? Wq : ((t == 1) ? Wk : Wv);
      wqkv[i] = (bf16)src[(h * 64 + r) * 512 + k];
    } else {
      int j = i - 786432;
      wob[j] = (bf16)Wo[j];
    }
  }
}

// ---------------- fused kernel ----------------
// 512 threads, 8 batch elems (80 rows) per block. 1 block/CU. LDS 155648 B.
// phase 1: sA @0 [8 slabs][80 rows][128B] XOR-swizzled         81920
//          sB0 @81920, sB1 @106496: 2-head B chunk dbuf        2 x 24576
//          epilogue overlay: sQK0 @81920, sQK1 @104448 (22528 each),
//            vbuf2 @126976 [80][128] bf16 (v interleaved by head, 20480),
//            scp0 @147456, scp1 @151296 (3840 each)  -> end 155136
// phase 2 overlay: Ab0@0 Ab1@5120 | Bb0@10240 Bb1@43008 (end 75776)
//          lnb @0 [80][520] bf16 (83200) | partial @83200 | stats @85760
__global__ __launch_bounds__(512, 2) void kern_fused(
    const float* __restrict__ x, const float* __restrict__ Wf,
    const float* __restrict__ bfv, const bf16* __restrict__ wqkv,
    const float* __restrict__ bq, const float* __restrict__ bk,
    const float* __restrict__ bv, bf16* __restrict__ O,
    const bf16* __restrict__ wob, const float* __restrict__ bo,
    const float* __restrict__ gamma, const float* __restrict__ beta,
    float* __restrict__ out) {
  __shared__ __align__(16) char smem[155648];
  char* sA  = smem;
  char* sB0 = smem + 81920;
  char* sB1 = smem + 106496;
  bf16* vbuf2 = (bf16*)(smem + 126976);

  const int tid = threadIdx.x;
  const int wave = tid >> 6;
  const int lane = tid & 63;
  const int lm = lane & 15;
  const int lg = lane >> 4;
  const int wm = wave >> 2;
  const int wn = wave & 3;
  const int b0 = blockIdx.x * 8;
  const int x7 = lm & 7;
  // staging lane geometry (paired-row layout; v6/phase-2 verified):
  const int srow  = lane >> 2;                       // row within 16-row copy
  const int sgran = (lane & 3) ^ ((lane >> 3) & 3);  // pre-swizzled granule

  // stage k-chunk j_ (32 k = 64B/row) of heads g_*2, g_*2+1 into buf_.
  // 24 copies of 1024B (8 lines = 16 rows); 3 per wave; dest wave-uniform.
#define STAGE1(buf_, g_, j_)                                                   \
  {                                                                            \
    _Pragma("unroll")                                                          \
    for (int jb = 0; jb < 3; ++jb) {                                           \
      int c = wave + 8 * jb;                                                   \
      int hh = c / 12;                                                         \
      int L0 = (c - hh * 12) * 8;                                              \
      async_copy16((buf_) + hh * 12288 + L0 * 128,                             \
          (const char*)wqkv + (size_t)((g_) * 2 + hh) * 196608 +               \
          (size_t)(L0 * 2 + srow) * 1024 + (size_t)(j_) * 64 + sgran * 16);    \
    }                                                                          \
  }

  // ---- prologue: stage (g=0, j=0) into sB0 (hides under P compute) ----
  STAGE1(sB0, 0, 0);

  // ---- compute P = relu(x*Wf + bf) into sA (80 real rows) ----
#pragma unroll
  for (int it = 0; it < 10; ++it) {
    int c = tid + it * 512;                // 5120 chunks: c = s*640 + r*8 + kcp
    int s = c / 640, rem = c - s * 640;
    int r = rem >> 3, kcp = rem & 7;
    int kc = kcp ^ (r & 7);
    int k = s * 64 + kc * 8;
    int bl = r / 10, f = r - bl * 10;
    float xv = x[(b0 + bl) * 10 + f];
    const float* wf = Wf + f * 512 + k;
    const float* bp = bfv + f * 512 + k;
    bf16x8 pv;
#pragma unroll
    for (int j = 0; j < 8; ++j) pv[j] = (bf16)fmaxf(xv * wf[j] + bp[j], 0.f);
    *(bf16x8*)(sA + s * 10240 + r * 128 + kcp * 16) = pv;
  }
  __syncthreads();   // P visible + stage(0,0) landed

  // B-frag LDS offsets are chunk-invariant: precompute per nt
  int noff[3];
#pragma unroll
  for (int nt = 0; nt < 3; ++nt) {
    int n = wn * 48 + nt * 16 + lm, line = n >> 1;
    noff[nt] = line * 128 + (n & 1) * 64 + ((lg ^ (line & 3)) << 4);
  }

  for (int g = 0; g < 4; ++g) {
    f32x4 acc[2][3][3];
#pragma unroll
    for (int e = 0; e < 2; ++e)
#pragma unroll
      for (int i = 0; i < 3; ++i)
#pragma unroll
        for (int j = 0; j < 3; ++j) { f32x4 z = {0.f, 0.f, 0.f, 0.f}; acc[e][i][j] = z; }

    for (int j = 0; j < 16; ++j) {       // 16 k-chunks of 32
      char* bufC = (j & 1) ? sB1 : sB0;
      char* bufN = (j & 1) ? sB0 : sB1;
      if (j != 15) {
        STAGE1(bufN, g, j + 1);
        asm volatile("s_waitcnt vmcnt(3)" ::: "memory");  // chunk j landed; j+1 in flight
      } else {
        asm volatile("s_waitcnt vmcnt(0)" ::: "memory");
      }
      __builtin_amdgcn_sched_barrier(0);
      __builtin_amdgcn_s_barrier();      // chunk j visible to all waves
      __builtin_amdgcn_sched_barrier(0);

      const char* sAj = sA + (j >> 1) * 10240;
      const int ch = (((j & 1) * 4 + lg) ^ x7) << 4;
      bf16x8 af[3], bfr[2][3];
#pragma unroll
      for (int mt = 0; mt < 3; ++mt)
        if (mt < 2 || wm == 0)
          af[mt] = *(const bf16x8*)(sAj + (wm * 48 + mt * 16 + lm) * 128 + ch);
#pragma unroll
      for (int e = 0; e < 2; ++e)
#pragma unroll
        for (int nt = 0; nt < 3; ++nt)
          bfr[e][nt] = *(const bf16x8*)(bufC + e * 12288 + noff[nt]);
      __builtin_amdgcn_s_setprio(1);
#pragma unroll
      for (int e = 0; e < 2; ++e)
#pragma unroll
        for (int mt = 0; mt < 3; ++mt)
          if (mt < 2 || wm == 0)
#pragma unroll
            for (int nt = 0; nt < 3; ++nt)
              acc[e][mt][nt] = __builtin_amdgcn_mfma_f32_16x16x32_bf16(af[mt], bfr[e][nt], acc[e][mt][nt], 0, 0, 0);
      __builtin_amdgcn_s_setprio(0);
      asm volatile("s_waitcnt lgkmcnt(0)" ::: "memory");  // bufC reads retired
      __builtin_amdgcn_sched_barrier(0);
      __builtin_amdgcn_s_barrier();      // release bufC for re-stage
      __builtin_amdgcn_sched_barrier(0);
    }

    // ---- paired epilogue: heads g*2, g*2+1 (sB region is scratch now) ----
    // spill q,k (+bias) -> sQK[e] (swizzled), v (+bias) -> vbuf2 interleaved
#pragma unroll
    for (int e = 0; e < 2; ++e) {
      const int h = g * 2 + e;
      char* sQKe = smem + 81920 + e * 22528;
      float bias[3];
#pragma unroll
      for (int nt = 0; nt < 3; ++nt) {
        int col = wn * 48 + nt * 16 + lm;
        bias[nt] = (col < 64) ? bq[h * 64 + col]
                 : (col < 128) ? bk[h * 64 + col - 64]
                 : bv[h * 64 + col - 128];
      }
#pragma unroll
      for (int mt = 0; mt < 3; ++mt) {
        int rowb = wm * 48 + mt * 16 + lg * 4;
        if (rowb < 80) {
#pragma unroll
          for (int r = 0; r < 4; ++r) {
            int rw = rowb + r;
#pragma unroll
            for (int nt = 0; nt < 3; ++nt) {
              int col = wn * 48 + nt * 16 + lm;
              float val = acc[e][mt][nt][r] + bias[nt];
              if (col < 128)
                *(bf16*)(sQKe + rw * 256 + (((col >> 3) ^ (rw & 7)) << 4) + (col & 7) * 2) = (bf16)val;
              else
                vbuf2[rw * 128 + (col - 128) * 2 + e] = (bf16)val;
            }
          }
        }
      }
    }
    __syncthreads();   // qkv of both heads visible

    // ---- scores (MFMA) + shuffle-free softmax + PV, both heads; wave = batch ----
    {
      const int bb = wave;
      const int d = lane;
      uint32_t vvp[10];                    // packed v for both heads at (j, d)
#pragma unroll
      for (int jv = 0; jv < 10; ++jv)
        vvp[jv] = *(const uint32_t*)(vbuf2 + (bb * 10 + jv) * 128 + d * 2);
#pragma unroll
      for (int e = 0; e < 2; ++e) {
        const int h = g * 2 + e;
        const char* sQKe = smem + 81920 + e * 22528;
        float* scpe = (float*)(smem + 147456 + e * 3840);
        f32x4 sv = {0.f, 0.f, 0.f, 0.f};
        const int rowa = bb * 10 + lm;     // lm>=10: garbage rows, masked below
        const int x7r = rowa & 7;
#pragma unroll
        for (int kk = 0; kk < 2; ++kk) {
          bf16x8 qf = *(const bf16x8*)(sQKe + rowa * 256 + (((kk * 4 + lg) ^ x7r) << 4));
          bf16x8 kf = *(const bf16x8*)(sQKe + rowa * 256 + (((8 + kk * 4 + lg) ^ x7r) << 4));
          sv = __builtin_amdgcn_mfma_f32_16x16x32_bf16(qf, kf, sv, 0, 0, 0);
        }
        // store UNNORMALIZED exp (|score| <~ 10 analytically -> f32-safe; v6-verified)
#pragma unroll
        for (int r = 0; r < 4; ++r) {
          int i = lg * 4 + r;
          if (i < 10 && lm < 12)
            scpe[(bb * 10 + i) * 12 + lm] = (lm < 10) ? __expf(sv[r] * 0.125f) : 0.f;
        }
        // PV (lane <-> d); denominator folded in; wave-local (no barrier)
        float vv[10];
#pragma unroll
        for (int jv = 0; jv < 10; ++jv)
          vv[jv] = __uint_as_float((e == 0) ? (vvp[jv] << 16) : (vvp[jv] & 0xffff0000u));
        bf16* Obp = O + ((size_t)(b0 + bb) * 10) * 512 + h * 64 + d;
#pragma unroll
        for (int i = 0; i < 10; ++i) {
          const float* ar = scpe + (bb * 10 + i) * 12;
          f32x4 a0 = *(const f32x4*)ar;
          f32x4 a1 = *(const f32x4*)(ar + 4);
          f32x4 a2 = *(const f32x4*)(ar + 8);   // [8],[9] real; [10],[11] zero
          float ssum = a0[0] + a0[1] + a0[2] + a0[3] + a1[0] + a1[1] + a1[2] + a1[3] + a2[0] + a2[1];
          float o = a0[0] * vv[0] + a0[1] * vv[1] + a0[2] * vv[2] + a0[3] * vv[3]
                  + a1[0] * vv[4] + a1[1] * vv[5] + a1[2] * vv[6] + a1[3] * vv[7]
                  + a2[0] * vv[8] + a2[1] * vv[9];
          Obp[(size_t)i * 512] = (bf16)(o / ssum);   // 64 lanes x 2B = 128B contiguous
        }
      }
    }
    __syncthreads();   // epilogue buffers dead; O stores drained

    if (g < 3) {       // stage first chunk of next head-pair (sB0: t even)
      STAGE1(sB0, g + 1, 0);
      asm volatile("s_waitcnt vmcnt(0)" ::: "memory");
      __builtin_amdgcn_sched_barrier(0);
      __builtin_amdgcn_s_barrier();
      __builtin_amdgcn_sched_barrier(0);
    }
  }

  // ================= Phase 2: O @ Wo^T + bo -> LN -> sum over F =================
  // v4 verbatim: BK=32, dbuf A+B, raw barriers + counted vmcnt, paired-row layout.
  {
    char* Ab0 = smem;
    char* Ab1 = smem + 5120;
    char* Bb0 = smem + 10240;
    char* Bb1 = smem + 43008;
    float* partial = (float*)(smem + 83200);  // [80][4][2]
    float* stats   = (float*)(smem + 85760);  // [80][2]
    const char* Ob = (const char*)(O + (size_t)blockIdx.x * 80 * 512);
    const char* Wb = (const char*)wob;

    f32x4 acc[3][8];
#pragma unroll
    for (int i = 0; i < 3; ++i)
#pragma unroll
      for (int j = 0; j < 8; ++j) { f32x4 z = {0.f, 0.f, 0.f, 0.f}; acc[i][j] = z; }

#define STAGE2(AbN, BbN, s_)                                                     \
    {                                                                            \
      size_t co = (size_t)(s_) * 64 + sgran * 16;                                \
      _Pragma("unroll")                                                          \
      for (int j = 0; j < 4; ++j) {                                              \
        int R0 = (wave * 4 + j) * 16;                                            \
        async_copy16((BbN) + R0 * 64, Wb + (size_t)(R0 + srow) * 1024 + co);     \
      }                                                                          \
      if (wave < 5) {                                                            \
        int R0 = wave * 16;                                                      \
        async_copy16((AbN) + R0 * 64, Ob + (size_t)(R0 + srow) * 1024 + co);     \
      }                                                                          \
    }

    STAGE2(Ab0, Bb0, 0);                   // prologue

    for (int s = 0; s < 16; ++s) {
      char* AbC = (s & 1) ? Ab1 : Ab0;
      char* BbC = (s & 1) ? Bb1 : Bb0;
      char* AbN = (s & 1) ? Ab0 : Ab1;
      char* BbN = (s & 1) ? Bb0 : Bb1;
      if (s != 15) {
        STAGE2(AbN, BbN, s + 1);
        if (wave < 5) asm volatile("s_waitcnt vmcnt(5)" ::: "memory");
        else          asm volatile("s_waitcnt vmcnt(4)" ::: "memory");
      } else {
        asm volatile("s_waitcnt vmcnt(0)" ::: "memory");
      }
      __builtin_amdgcn_sched_barrier(0);
      __builtin_amdgcn_s_barrier();        // slab s visible
      __builtin_amdgcn_sched_barrier(0);

      bf16x8 a2[3], b2[8];
#pragma unroll
      for (int mt = 0; mt < 3; ++mt)
        if (mt < 2 || wm == 0) {
          int m = wm * 48 + mt * 16 + lm;
          a2[mt] = *(const bf16x8*)(AbC + (m >> 1) * 128 + (m & 1) * 64 + (((lg ^ ((m >> 1) & 3))) << 4));
        }
#pragma unroll
      for (int nt = 0; nt < 8; ++nt) {
        int n = wn * 128 + nt * 16 + lm;
        b2[nt] = *(const bf16x8*)(BbC + (n >> 1) * 128 + (n & 1) * 64 + (((lg ^ ((n >> 1) & 3))) << 4));
      }
      __builtin_amdgcn_s_setprio(1);
#pragma unroll
      for (int mt = 0; mt < 3; ++mt)
        if (mt < 2 || wm == 0)
#pragma unroll
          for (int nt = 0; nt < 8; ++nt)
            acc[mt][nt] = __builtin_amdgcn_mfma_f32_16x16x32_bf16(a2[mt], b2[nt], acc[mt][nt], 0, 0, 0);
      __builtin_amdgcn_s_setprio(0);

      asm volatile("s_waitcnt lgkmcnt(0)" ::: "memory");
      __builtin_amdgcn_sched_barrier(0);
      __builtin_amdgcn_s_barrier();        // release slab s buffers
      __builtin_amdgcn_sched_barrier(0);
    }

    // + bias
#pragma unroll
    for (int nt = 0; nt < 8; ++nt) {
      float bb = bo[wn * 128 + nt * 16 + lm];
#pragma unroll
      for (int mt = 0; mt < 3; ++mt)
#pragma unroll
        for (int r = 0; r < 4; ++r) acc[mt][nt][r] += bb;
    }

    // per-row mean/var: lane-local over 8 nt, then xor-shuffle across 16-lane col group
#pragma unroll
    for (int mt = 0; mt < 3; ++mt)
#pragma unroll
      for (int r = 0; r < 4; ++r) {
        float s1 = 0.f, s2 = 0.f;
#pragma unroll
        for (int nt = 0; nt < 8; ++nt) { float v = acc[mt][nt][r]; s1 += v; s2 += v * v; }
#pragma unroll
        for (int off = 1; off < 16; off <<= 1) {
          s1 += __shfl_xor(s1, off);
          s2 += __shfl_xor(s2, off);
        }
        if (lm == 0) {
          int row = wm * 48 + mt * 16 + lg * 4 + r;
          if (row < 80) {
            partial[(row * 4 + wn) * 2]     = s1;
            partial[(row * 4 + wn) * 2 + 1] = s2;
          }
        }
      }
    __syncthreads();
    if (tid < 80) {
      float s1 = 0.f, s2 = 0.f;
#pragma unroll
      for (int w = 0; w < 4; ++w) {
        s1 += partial[(tid * 4 + w) * 2];
        s2 += partial[(tid * 4 + w) * 2 + 1];
      }
      float mu = s1 * (1.f / 512.f);
      float var = s2 * (1.f / 512.f) - mu * mu;
      stats[tid * 2]     = mu;
      stats[tid * 2 + 1] = rsqrtf(var + EPS);
    }
    __syncthreads();
    // normalized values -> LDS bf16 (GEMM buffers dead), stride 520
    bf16* lnb = (bf16*)smem;
#pragma unroll
    for (int mt = 0; mt < 3; ++mt)
#pragma unroll
      for (int r = 0; r < 4; ++r) {
        int row = wm * 48 + mt * 16 + lg * 4 + r;
        if (row < 80) {
          float mu = stats[row * 2], rr = stats[row * 2 + 1];
#pragma unroll
          for (int nt = 0; nt < 8; ++nt) {
            int col = wn * 128 + nt * 16 + lm;
            lnb[row * 520 + col] = (bf16)((acc[mt][nt][r] - mu) * rr);
          }
        }
      }
    __syncthreads();
    // out[b,n] = gamma[n]*sum_f lnv + 10*beta[n]
#pragma unroll
    for (int u = 0; u < 8; ++u) {
      int id = tid + u * 512;              // 4096 outputs: 8b x 512n
      int b = id >> 9, n = id & 511;
      float ssum = 0.f;
#pragma unroll
      for (int f = 0; f < 10; ++f) ssum += (float)lnb[(b * 10 + f) * 520 + n];
      out[((size_t)blockIdx.x * 8 + b) * 512 + n] = gamma[n] * ssum + 10.f * beta[n];
    }
  }
#undef STAGE1
#undef STAGE2
}

extern "C" void kernel_launch(void* const* d_in, const int* in_sizes, int n_in,
                              void* d_out, int out_size, void* d_ws, size_t ws_size,
                              hipStream_t stream) {
  const float* x     = (const float*)d_in[0];
  const float* Wf    = (const float*)d_in[1];
  const float* bfv   = (const float*)d_in[2];
  const float* Wq    = (const float*)d_in[3];
  const float* Wk    = (const float*)d_in[4];
  const float* Wv    = (const float*)d_in[5];
  const float* bq    = (const float*)d_in[6];
  const float* bk    = (const float*)d_in[7];
  const float* bv    = (const float*)d_in[8];
  const float* Wo    = (const float*)d_in[9];
  const float* bo    = (const float*)d_in[10];
  const float* gamma = (const float*)d_in[11];
  const float* beta  = (const float*)d_in[12];
  float* out = (float*)d_out;

  char* ws = (char*)d_ws;
  bf16* O    = (bf16*)ws;                              // 167,772,160 B
  bf16* wqkv = (bf16*)(ws + O_BYTES);                  // 1,572,864 B
  bf16* wob  = (bf16*)(ws + O_BYTES + WQKV_BYTES);     // 524,288 B

  pack_weights<<<1024, 256, 0, stream>>>(Wq, Wk, Wv, Wo, wqkv, wob);
  kern_fused<<<2048, 512, 0, stream>>>(x, Wf, bfv, wqkv, bq, bk, bv, O,
                                       wob, bo, gamma, beta, out);
}

// Round 7
// 767.794 us; speedup vs baseline: 1.5565x; 1.2536x over previous
//
#include <hip/hip_runtime.h>
#include <stdint.h>

// ParallelFcWithAttention: B=16384, F=10, D=512, H=8, DH=64
// v8: decouple the CU. 256-thread / 4-batch blocks, LDS 74KB -> 2 independent
// blocks per CU (same 8 waves/CU as v4 but no cross-block barrier lockstep:
// one block computes while the other drains/stages). Per-wave register shapes
// identical to v4-proven (acc[3][3] p1, acc[3][8] p2) -> no spill.
// Phase 1: BK=32, B dbuf 2x12KB, v4 counted-vmcnt(3) pattern, 1 head/pass.
// Phase 2: v4 BK=32 dbuf structure scaled to 4 waves.

typedef __bf16 bf16;
typedef __bf16 bf16x8 __attribute__((ext_vector_type(8)));
typedef float f32x4 __attribute__((ext_vector_type(4)));

#define EPS 1e-5f

static constexpr size_t O_ELEMS   = (size_t)16384 * 10 * 512;   // 83,886,080
static constexpr size_t O_BYTES   = O_ELEMS * 2;                // 167,772,160
static constexpr size_t WQKV_BYTES = (size_t)8 * 192 * 512 * 2; // 1,572,864

__device__ __forceinline__ void async_copy16(void* lds, const void* g) {
  // wave-uniform LDS base; HW scatters lane i at base + i*16; global addr per-lane
  __builtin_amdgcn_global_load_lds(
      (const __attribute__((address_space(1))) uint32_t*)g,
      (__attribute__((address_space(3))) uint32_t*)lds, 16, 0, 0);
}

// ---------------- pack weights to bf16 ----------------
// wqkv layout: [h][0:64 = Wq rows h*64.., 64:128 = Wk, 128:192 = Wv][512]
__global__ __launch_bounds__(256) void pack_weights(
    const float* __restrict__ Wq, const float* __restrict__ Wk,
    const float* __restrict__ Wv, const float* __restrict__ Wo,
    bf16* __restrict__ wqkv, bf16* __restrict__ wob) {
  int idx = blockIdx.x * 256 + threadIdx.x;
#pragma unroll
  for (int u = 0; u < 4; ++u) {
    int i = idx + u * 262144;
    if (i < 786432) {
      int pr = i >> 9, k = i & 511;
      int h = pr / 192, w = pr - h * 192;
      int t = w >> 6, r = w & 63;
      const float* src = (t == 0) ? Wq : ((t == 1) ? Wk : Wv);
      wqkv[i] = (bf16)src[(h * 64 + r) * 512 + k];
    } else {
      int j = i - 786432;
      wob[j] = (bf16)Wo[j];
    }
  }
}

// ---------------- fused kernel ----------------
// 256 threads (4 waves), 4 batch elems (40 rows, pad 48) per block. 2 blocks/CU.
// LDS (75776 B):
//   phase 1: sA  @0     [8 slabs][40 rows][128B] XOR-swizzled, +2KB pad-read guard  43008
//            sB0 @43008, sB1 @55296: B k-chunk dbuf (12288 each; [96 lines][128B]
//              paired-row layout, 2 rows/line, XOR granules)
//            epilogue: sQK = sB1 overlay (rows<40 written), vbuf @67584 [40][64]
//              bf16 (5120), scp @72704 [4][10][12] f32 (1920)   -> end 74624
//   phase 2: Ab0 @0 (3072), Ab1 @3072 | Bb0 @6144, Bb1 @38912 (32768 each, end 71680)
//            partial @71680 [40][4][2] | stats @72960 [40][2]
//            lnb overlay @0 [40][520] bf16 (41600, GEMM bufs dead)
__global__ __launch_bounds__(256, 2) void kern_fused(
    const float* __restrict__ x, const float* __restrict__ Wf,
    const float* __restrict__ bfv, const bf16* __restrict__ wqkv,
    const float* __restrict__ bq, const float* __restrict__ bk,
    const float* __restrict__ bv, bf16* __restrict__ O,
    const bf16* __restrict__ wob, const float* __restrict__ bo,
    const float* __restrict__ gamma, const float* __restrict__ beta,
    float* __restrict__ out) {
  __shared__ __align__(16) char smem[75776];
  char* sA  = smem;                         // 40960 + 2048 guard
  char* sB0 = smem + 43008;
  char* sB1 = smem + 55296;
  char* sQK = sB1;                          // epilogue overlay
  bf16* vbuf = (bf16*)(smem + 67584);       // [40][64]
  float* scp = (float*)(smem + 72704);      // [4][10][12]

  const int tid = threadIdx.x;
  const int wave = tid >> 6;                // == wn (4 waves, N-split only)
  const int lane = tid & 63;
  const int lm = lane & 15;
  const int lg = lane >> 4;
  const int wn = wave;
  const int b0 = blockIdx.x * 4;
  const int x7 = lm & 7;
  // staging lane geometry (paired-row layout, v7-verified formulas):
  const int srow  = lane >> 2;                       // row within 16-row copy
  const int sgran = (lane & 3) ^ ((lane >> 3) & 3);  // pre-swizzled granule

  // stage k-chunk j_ (32 k = 64B/row) of head h_: 12 x 1KB copies, 3/wave
#define STAGE1(buf_, h_, j_)                                                   \
  {                                                                            \
    _Pragma("unroll")                                                          \
    for (int jb = 0; jb < 3; ++jb) {                                           \
      int c = wave + 4 * jb;                                                   \
      async_copy16((buf_) + c * 1024,                                          \
          (const char*)wqkv + (size_t)(h_) * 196608 +                          \
          (size_t)(c * 16 + srow) * 1024 + (size_t)(j_) * 64 + sgran * 16);    \
    }                                                                          \
  }

  // ---- prologue: stage (h=0, j=0) into sB0 (hides under P compute) ----
  STAGE1(sB0, 0, 0);

  // ---- compute P = relu(x*Wf + bf) into sA (40 real rows; pad rows unwritten,
  //      garbage reads land in guard / next slab and are discarded) ----
#pragma unroll
  for (int it = 0; it < 10; ++it) {
    int c = tid + it * 256;                // 2560 chunks: c = s*320 + r*8 + kcp
    int s = c / 320, rem = c - s * 320;
    int r = rem >> 3, kcp = rem & 7;
    int kc = kcp ^ (r & 7);
    int k = s * 64 + kc * 8;
    int bl = r / 10, f = r - bl * 10;
    float xv = x[(b0 + bl) * 10 + f];
    const float* wf = Wf + f * 512 + k;
    const float* bp = bfv + f * 512 + k;
    bf16x8 pv;
#pragma unroll
    for (int j = 0; j < 8; ++j) pv[j] = (bf16)fmaxf(xv * wf[j] + bp[j], 0.f);
    *(bf16x8*)(sA + s * 5120 + r * 128 + kcp * 16) = pv;
  }
  __syncthreads();   // P visible + stage(0,0) landed

  // B-frag LDS offsets are chunk-invariant: precompute per nt
  int noff[3];
#pragma unroll
  for (int nt = 0; nt < 3; ++nt) {
    int n = wn * 48 + nt * 16 + lm, line = n >> 1;
    noff[nt] = line * 128 + (n & 1) * 64 + ((lg ^ (line & 3)) << 4);
  }

  for (int h = 0; h < 8; ++h) {
    f32x4 acc[3][3];
#pragma unroll
    for (int i = 0; i < 3; ++i)
#pragma unroll
      for (int j = 0; j < 3; ++j) { f32x4 z = {0.f, 0.f, 0.f, 0.f}; acc[i][j] = z; }

    for (int j = 0; j < 16; ++j) {       // 16 k-chunks of 32
      char* bufC = (j & 1) ? sB1 : sB0;
      char* bufN = (j & 1) ? sB0 : sB1;
      if (j < 15) {
        STAGE1(bufN, h, j + 1);
        asm volatile("s_waitcnt vmcnt(3)" ::: "memory");  // chunk j landed
      } else if (h < 7) {
        STAGE1(bufN, h + 1, 0);                           // next head chunk 0 -> sB0
        asm volatile("s_waitcnt vmcnt(3)" ::: "memory");
      } else {
        asm volatile("s_waitcnt vmcnt(0)" ::: "memory");
      }
      __builtin_amdgcn_sched_barrier(0);
      __builtin_amdgcn_s_barrier();      // chunk j visible to all waves
      __builtin_amdgcn_sched_barrier(0);

      const char* sAj = sA + (j >> 1) * 5120;
      const int ch = (((j & 1) * 4 + lg) ^ x7) << 4;
      bf16x8 af[3], bfr[3];
#pragma unroll
      for (int mt = 0; mt < 3; ++mt)
        af[mt] = *(const bf16x8*)(sAj + (mt * 16 + lm) * 128 + ch);
#pragma unroll
      for (int nt = 0; nt < 3; ++nt)
        bfr[nt] = *(const bf16x8*)(bufC + noff[nt]);
      __builtin_amdgcn_s_setprio(1);
#pragma unroll
      for (int mt = 0; mt < 3; ++mt)
#pragma unroll
        for (int nt = 0; nt < 3; ++nt)
          acc[mt][nt] = __builtin_amdgcn_mfma_f32_16x16x32_bf16(af[mt], bfr[nt], acc[mt][nt], 0, 0, 0);
      __builtin_amdgcn_s_setprio(0);
      asm volatile("s_waitcnt lgkmcnt(0)" ::: "memory");  // bufC reads retired
      __builtin_amdgcn_sched_barrier(0);
      __builtin_amdgcn_s_barrier();      // release bufC for re-stage
      __builtin_amdgcn_sched_barrier(0);
    }

    // ---- epilogue head h (sB1 is scratch; sB0 holds in-flight next-head chunk 0) ----
    // spill q,k (+bias) -> sQK(=sB1) swizzled, v (+bias) -> vbuf
    {
      float bias[3];
#pragma unroll
      for (int nt = 0; nt < 3; ++nt) {
        int col = wn * 48 + nt * 16 + lm;
        bias[nt] = (col < 64) ? bq[h * 64 + col]
                 : (col < 128) ? bk[h * 64 + col - 64]
                 : bv[h * 64 + col - 128];
      }
#pragma unroll
      for (int mt = 0; mt < 3; ++mt) {
        int rowb = mt * 16 + lg * 4;
#pragma unroll
        for (int r = 0; r < 4; ++r) {
          int rw = rowb + r;
          if (rw < 40) {
#pragma unroll
            for (int nt = 0; nt < 3; ++nt) {
              int col = wn * 48 + nt * 16 + lm;
              float val = acc[mt][nt][r] + bias[nt];
              if (col < 128)
                *(bf16*)(sQK + rw * 256 + (((col >> 3) ^ (rw & 7)) << 4) + (col & 7) * 2) = (bf16)val;
              else
                vbuf[rw * 64 + (col - 128)] = (bf16)val;
            }
          }
        }
      }
    }
    __syncthreads();   // qkv visible to all waves

    // scores via MFMA (wave = local batch); shuffle-free softmax: store
    // UNNORMALIZED exp (|score| small, f32-safe; v6/v7-verified), denom in PV
    {
      const int bb = wave;
      f32x4 sv = {0.f, 0.f, 0.f, 0.f};
      const int rowa = bb * 10 + lm;     // lm>=10: stale-but-finite rows, masked
      const int x7r = rowa & 7;
#pragma unroll
      for (int kk = 0; kk < 2; ++kk) {
        bf16x8 qf = *(const bf16x8*)(sQK + rowa * 256 + (((kk * 4 + lg) ^ x7r) << 4));
        bf16x8 kf = *(const bf16x8*)(sQK + rowa * 256 + (((8 + kk * 4 + lg) ^ x7r) << 4));
        sv = __builtin_amdgcn_mfma_f32_16x16x32_bf16(qf, kf, sv, 0, 0, 0);
      }
#pragma unroll
      for (int r = 0; r < 4; ++r) {
        int i = lg * 4 + r;
        if (i < 10 && lm < 12)
          scp[(bb * 10 + i) * 12 + lm] = (lm < 10) ? __expf(sv[r] * 0.125f) : 0.f;
      }
      // PV (lane <-> d); wave-local (scp/vbuf for bb written/covered) -> no barrier
      const int d = lane;
      float vv[10];
#pragma unroll
      for (int jv = 0; jv < 10; ++jv) vv[jv] = (float)vbuf[(bb * 10 + jv) * 64 + d];
      bf16* Obp = O + ((size_t)(b0 + bb) * 10) * 512 + h * 64 + d;
#pragma unroll
      for (int i = 0; i < 10; ++i) {
        const float* ar = scp + (bb * 10 + i) * 12;
        f32x4 a0 = *(const f32x4*)ar;
        f32x4 a1 = *(const f32x4*)(ar + 4);
        f32x4 a2 = *(const f32x4*)(ar + 8);   // [8],[9] real; [10],[11] zero
        float ssum = a0[0] + a0[1] + a0[2] + a0[3] + a1[0] + a1[1] + a1[2] + a1[3] + a2[0] + a2[1];
        float o = a0[0] * vv[0] + a0[1] * vv[1] + a0[2] * vv[2] + a0[3] * vv[3]
                + a1[0] * vv[4] + a1[1] * vv[5] + a1[2] * vv[6] + a1[3] * vv[7]
                + a2[0] * vv[8] + a2[1] * vv[9];
        Obp[(size_t)i * 512] = (bf16)(o / ssum);   // 64 lanes x 2B = 128B contiguous
      }
    }
    __syncthreads();   // drain (incl. O stores + next-head stage); sB1 reusable
  }

  // ================= Phase 2: O @ Wo^T + bo -> LN -> sum over F =================
  // BK=32 dbuf A+B, counted vmcnt, paired-row layout (v4-proven, 4-wave scale).
  {
    char* Ab0 = smem;
    char* Ab1 = smem + 3072;
    char* Bb0 = smem + 6144;
    char* Bb1 = smem + 38912;
    float* partial = (float*)(smem + 71680);  // [40][4][2]
    float* stats   = (float*)(smem + 72960);  // [40][2]
    const char* Ob = (const char*)(O + (size_t)blockIdx.x * 40 * 512);
    const char* Wb = (const char*)wob;

    f32x4 acc[3][8];
#pragma unroll
    for (int i = 0; i < 3; ++i)
#pragma unroll
      for (int j = 0; j < 8; ++j) { f32x4 z = {0.f, 0.f, 0.f, 0.f}; acc[i][j] = z; }

    // B: 32 copies (8/wave); A: 3 copies (waves 0-2), pad rows clamp to 39
#define STAGE2(AbN, BbN, s_)                                                     \
    {                                                                            \
      size_t co = (size_t)(s_) * 64 + sgran * 16;                                \
      _Pragma("unroll")                                                          \
      for (int jj = 0; jj < 8; ++jj) {                                           \
        int c = wave + 4 * jj;                                                   \
        async_copy16((BbN) + c * 1024, Wb + (size_t)(c * 16 + srow) * 1024 + co);\
      }                                                                          \
      if (wave < 3) {                                                            \
        int rs = wave * 16 + srow; if (rs > 39) rs = 39;                         \
        async_copy16((AbN) + wave * 1024, Ob + (size_t)rs * 1024 + co);          \
      }                                                                          \
    }

    STAGE2(Ab0, Bb0, 0);                   // prologue

    for (int s = 0; s < 16; ++s) {
      char* AbC = (s & 1) ? Ab1 : Ab0;
      char* BbC = (s & 1) ? Bb1 : Bb0;
      char* AbN = (s & 1) ? Ab0 : Ab1;
      char* BbN = (s & 1) ? Bb0 : Bb1;
      if (s != 15) {
        STAGE2(AbN, BbN, s + 1);
        if (wave < 3) asm volatile("s_waitcnt vmcnt(9)" ::: "memory");
        else          asm volatile("s_waitcnt vmcnt(8)" ::: "memory");
      } else {
        asm volatile("s_waitcnt vmcnt(0)" ::: "memory");
      }
      __builtin_amdgcn_sched_barrier(0);
      __builtin_amdgcn_s_barrier();        // slab s visible
      __builtin_amdgcn_sched_barrier(0);

      bf16x8 a2[3], b2[8];
#pragma unroll
      for (int mt = 0; mt < 3; ++mt) {
        int m = mt * 16 + lm, line = m >> 1;
        a2[mt] = *(const bf16x8*)(AbC + line * 128 + (m & 1) * 64 + ((lg ^ (line & 3)) << 4));
      }
#pragma unroll
      for (int nt = 0; nt < 8; ++nt) {
        int n = wn * 128 + nt * 16 + lm, line = n >> 1;
        b2[nt] = *(const bf16x8*)(BbC + line * 128 + (n & 1) * 64 + ((lg ^ (line & 3)) << 4));
      }
      __builtin_amdgcn_s_setprio(1);
#pragma unroll
      for (int mt = 0; mt < 3; ++mt)
#pragma unroll
        for (int nt = 0; nt < 8; ++nt)
          acc[mt][nt] = __builtin_amdgcn_mfma_f32_16x16x32_bf16(a2[mt], b2[nt], acc[mt][nt], 0, 0, 0);
      __builtin_amdgcn_s_setprio(0);

      asm volatile("s_waitcnt lgkmcnt(0)" ::: "memory");
      __builtin_amdgcn_sched_barrier(0);
      __builtin_amdgcn_s_barrier();        // release slab s buffers
      __builtin_amdgcn_sched_barrier(0);
    }

    // + bias
#pragma unroll
    for (int nt = 0; nt < 8; ++nt) {
      float bb = bo[wn * 128 + nt * 16 + lm];
#pragma unroll
      for (int mt = 0; mt < 3; ++mt)
#pragma unroll
        for (int r = 0; r < 4; ++r) acc[mt][nt][r] += bb;
    }

    // per-row mean/var: lane-local over 8 nt, then xor-shuffle across 16-lane col group
#pragma unroll
    for (int mt = 0; mt < 3; ++mt)
#pragma unroll
      for (int r = 0; r < 4; ++r) {
        float s1 = 0.f, s2 = 0.f;
#pragma unroll
        for (int nt = 0; nt < 8; ++nt) { float v = acc[mt][nt][r]; s1 += v; s2 += v * v; }
#pragma unroll
        for (int off = 1; off < 16; off <<= 1) {
          s1 += __shfl_xor(s1, off);
          s2 += __shfl_xor(s2, off);
        }
        if (lm == 0) {
          int row = mt * 16 + lg * 4 + r;
          if (row < 40) {
            partial[(row * 4 + wn) * 2]     = s1;
            partial[(row * 4 + wn) * 2 + 1] = s2;
          }
        }
      }
    __syncthreads();
    if (tid < 40) {
      float s1 = 0.f, s2 = 0.f;
#pragma unroll
      for (int w = 0; w < 4; ++w) {
        s1 += partial[(tid * 4 + w) * 2];
        s2 += partial[(tid * 4 + w) * 2 + 1];
      }
      float mu = s1 * (1.f / 512.f);
      float var = s2 * (1.f / 512.f) - mu * mu;
      stats[tid * 2]     = mu;
      stats[tid * 2 + 1] = rsqrtf(var + EPS);
    }
    __syncthreads();
    // normalized values -> LDS bf16 (GEMM buffers dead), stride 520
    bf16* lnb = (bf16*)smem;
#pragma unroll
    for (int mt = 0; mt < 3; ++mt)
#pragma unroll
      for (int r = 0; r < 4; ++r) {
        int row = mt * 16 + lg * 4 + r;
        if (row < 40) {
          float mu = stats[row * 2], rr = stats[row * 2 + 1];
#pragma unroll
          for (int nt = 0; nt < 8; ++nt) {
            int col = wn * 128 + nt * 16 + lm;
            lnb[row * 520 + col] = (bf16)((acc[mt][nt][r] - mu) * rr);
          }
        }
      }
    __syncthreads();
    // out[b,n] = gamma[n]*sum_f lnv + 10*beta[n]
#pragma unroll
    for (int u = 0; u < 8; ++u) {
      int id = tid + u * 256;              // 2048 outputs: 4b x 512n
      int b = id >> 9, n = id & 511;
      float ssum = 0.f;
#pragma unroll
      for (int f = 0; f < 10; ++f) ssum += (float)lnb[(b * 10 + f) * 520 + n];
      out[((size_t)blockIdx.x * 4 + b) * 512 + n] = gamma[n] * ssum + 10.f * beta[n];
    }
  }
#undef STAGE1
#undef STAGE2
}

extern "C" void kernel_launch(void* const* d_in, const int* in_sizes, int n_in,
                              void* d_out, int out_size, void* d_ws, size_t ws_size,
                              hipStream_t stream) {
  const float* x     = (const float*)d_in[0];
  const float* Wf    = (const float*)d_in[1];
  const float* bfv   = (const float*)d_in[2];
  const float* Wq    = (const float*)d_in[3];
  const float* Wk    = (const float*)d_in[4];
  const float* Wv    = (const float*)d_in[5];
  const float* bq    = (const float*)d_in[6];
  const float* bk    = (const float*)d_in[7];
  const float* bv    = (const float*)d_in[8];
  const float* Wo    = (const float*)d_in[9];
  const float* bo    = (const float*)d_in[10];
  const float* gamma = (const float*)d_in[11];
  const float* beta  = (const float*)d_in[12];
  float* out = (float*)d_out;

  char* ws = (char*)d_ws;
  bf16* O    = (bf16*)ws;                              // 167,772,160 B
  bf16* wqkv = (bf16*)(ws + O_BYTES);                  // 1,572,864 B
  bf16* wob  = (bf16*)(ws + O_BYTES + WQKV_BYTES);     // 524,288 B

  pack_weights<<<1024, 256, 0, stream>>>(Wq, Wk, Wv, Wo, wqkv, wob);
  kern_fused<<<4096, 256, 0, stream>>>(x, Wf, bfv, wqkv, bq, bk, bv, O,
                                       wob, bo, gamma, beta, out);
}